// Round 4
// baseline (396.198 us; speedup 1.0000x reference)
//
#include <hip/hip_runtime.h>
#include <stdint.h>

#define E_EDGES 131072
#define NELEC 1024
#define NNUC 256
#define MAXCHUNK 256
#define NBLK 16          // hist/scatter blocks per type
#define UNPB 4           // nodes per update block

typedef unsigned short ushort_t;
typedef __attribute__((ext_vector_type(8))) short short8;
typedef __attribute__((ext_vector_type(4))) short short4_t;
typedef __attribute__((ext_vector_type(4))) float float4_t;
typedef __attribute__((ext_vector_type(8))) float float8_t;
typedef __attribute__((ext_vector_type(4))) int int4_t;
typedef __attribute__((ext_vector_type(2))) unsigned int uint2_t;

__device__ inline float silu_f(float x){ return x / (1.0f + expf(-x)); }

__device__ inline short f2bf_rne(float x){
    union { float f; uint32_t u; } a; a.f = x;
    return (short)((a.u + 0x7fffu + ((a.u >> 16) & 1u)) >> 16);
}
__device__ inline float bf2f(short h){
    union { uint32_t u; float f; } a; a.u = ((uint32_t)(uint16_t)h) << 16;
    return a.f;
}
__device__ inline ushort_t bfu(float x){ return (ushort_t)f2bf_rne(x); }
__device__ inline float asf_lo(uint32_t u){ union { uint32_t u; float f; } a; a.u = u << 16; return a.f; }
__device__ inline float asf_hi(uint32_t u){ union { uint32_t u; float f; } a; a.u = u & 0xFFFF0000u; return a.f; }

// ================= prep: gather tables + W_w swizzle + out-init + histogram ==
// blocks: [0,288) h/gather tables (8 nodes each) | [288,291) wswizzle
//         [291,547) out-init | [547,595) histogram
__global__ __launch_bounds__(256) void prep_kernel(
    const float* __restrict__ s_elec, const float* __restrict__ v_elec,
    const float* __restrict__ s_nuc,  const float* __restrict__ v_nuc,
    const float* __restrict__ W_h1, const float* __restrict__ W_h2,
    const float* __restrict__ W_w,
    const int* __restrict__ receivers,
    ushort_t* __restrict__ tabA, ushort_t* __restrict__ tabB,
    short* __restrict__ fragH, short* __restrict__ fragL,
    int* __restrict__ bh, float* __restrict__ out)
{
    int b = blockIdx.x, tid = threadIdx.x;
    __shared__ float sls[8][64];
    __shared__ float hidls[128][8];
    __shared__ int hist[1024];

    if (b < 288){
        int t, node0;
        if (b < 32){ t = 0; node0 = b*8; }
        else if (b < 160){ t = 1; node0 = (b-32)*8; }
        else { t = 2; node0 = (b-160)*8; }
        int tp = t + 1;
        const float* src = (t == 0) ? s_nuc : s_elec;
        const float* vsrc = (t == 0) ? v_nuc : v_elec;
        long baseA = (t == 0) ? 0 : (t == 1 ? 32768 : 163840);
        long baseB = (t == 0) ? 0 : (t == 1 ? 65536 : 327680);
        for (int i = tid; i < 512; i += 256){ int n = i >> 6, f = i & 63; sls[n][f] = src[(node0+n)*64 + f]; }
        __syncthreads();
        {
            int j = tid & 127, nh = tid >> 7;
            const float* w1 = W_h1 + (long)tp*64*128;
            float a0=0,a1=0,a2=0,a3=0;
            #pragma unroll 8
            for (int f = 0; f < 64; f++){
                float w = w1[f*128 + j];
                a0 += sls[nh*4+0][f]*w; a1 += sls[nh*4+1][f]*w;
                a2 += sls[nh*4+2][f]*w; a3 += sls[nh*4+3][f]*w;
            }
            float4_t hv = { silu_f(a0), silu_f(a1), silu_f(a2), silu_f(a3) };
            *(float4_t*)&hidls[j][nh*4] = hv;
        }
        __syncthreads();
        if (tid < 192){
            const float* w2 = W_h2 + (long)tp*128*192;
            float acc[8] = {0,0,0,0,0,0,0,0};
            #pragma unroll 4
            for (int h = 0; h < 128; h++){
                float w = w2[h*192 + tid];
                float4_t ha = *(float4_t*)&hidls[h][0];
                float4_t hb = *(float4_t*)&hidls[h][4];
                acc[0]+=ha[0]*w; acc[1]+=ha[1]*w; acc[2]+=ha[2]*w; acc[3]+=ha[3]*w;
                acc[4]+=hb[0]*w; acc[5]+=hb[1]*w; acc[6]+=hb[2]*w; acc[7]+=hb[3]*w;
            }
            int p = tid >> 6, d2 = tid & 63;
            if (p == 0){
                #pragma unroll
                for (int n = 0; n < 8; n++)
                    tabA[baseA + (long)((node0+n)*64 + d2)*2 + 0] = bfu(acc[n]);
            } else if (p == 2){
                #pragma unroll
                for (int n = 0; n < 8; n++)
                    tabA[baseA + (long)((node0+n)*64 + d2)*2 + 1] = bfu(acc[n]);
            } else {
                #pragma unroll
                for (int n = 0; n < 8; n++){
                    const float* vp = vsrc + (long)(node0+n)*192 + d2*3;
                    long o = baseB + (long)((node0+n)*64 + d2)*4;
                    tabB[o+0] = bfu(acc[n]*vp[0]);
                    tabB[o+1] = bfu(acc[n]*vp[1]);
                    tabB[o+2] = bfu(acc[n]*vp[2]);
                }
            }
        }
    } else if (b < 291){
        int t = b - 288, tp = t + 1;
        const float* W = W_w + (long)tp*64*192;
        for (int idx = tid; idx < 12288; idx += 256){
            int j    = idx & 7;
            int lane = (idx >> 3) & 63;
            int ks   = (idx >> 9) & 1;
            int nt   = idx >> 10;
            int k = ks*32 + ((lane >> 4) & 3)*8 + j;
            int n = nt*16 + (lane & 15);
            float v = W[k*192 + n];
            short hi = f2bf_rne(v);
            short lo = f2bf_rne(v - bf2f(hi));
            fragH[t*12288 + idx] = hi;
            fragL[t*12288 + idx] = lo;
        }
    } else if (b < 547){
        int i = (b - 291)*256 + tid;
        int n = i >> 6, c4 = i & 63;
        float4_t v;
        if (c4 < 16) v = *(const float4_t*)(s_elec + n*64 + c4*4);
        else         v = *(const float4_t*)(v_elec + n*192 + (c4-16)*4);
        *(float4_t*)(out + n*256 + c4*4) = v;
    } else {
        int hb = b - 547, t = hb >> 4, blk = hb & 15;
        for (int i = tid; i < 1024; i += 256) hist[i] = 0;
        __syncthreads();
        long base = (long)(t+1)*E_EDGES + blk*8192;
        #pragma unroll 4
        for (int it = 0; it < 32; it++){
            int r = receivers[base + it*256 + tid];
            atomicAdd(&hist[r], 1);
        }
        __syncthreads();
        for (int bin = tid; bin < 1024; bin += 256)
            bh[(t*1024 + bin)*NBLK + blk] = hist[bin];
    }
}

// ================= scan: one block per type (types are independent, each sums
// to exactly E_EDGES, so global base = t*E_EDGES) =============================
__global__ __launch_bounds__(1024) void scan_kernel(int* __restrict__ bh,
                                                    int* __restrict__ offs,
                                                    int* __restrict__ counts){
    __shared__ int buf[1024];
    int t = blockIdx.x;
    int tid = threadIdx.x;
    int base = (t*1024 + tid)*NBLK;
    int vals[NBLK];
    const int4_t* p = (const int4_t*)(bh + base);
    int s = 0;
    #pragma unroll
    for (int j = 0; j < NBLK/4; j++){
        int4_t x = p[j];
        vals[j*4+0]=x[0]; vals[j*4+1]=x[1]; vals[j*4+2]=x[2]; vals[j*4+3]=x[3];
        s += x[0]+x[1]+x[2]+x[3];
    }
    buf[tid] = s;
    __syncthreads();
    int x = s;
    for (int off = 1; off < 1024; off <<= 1){
        int y = (tid >= off) ? buf[tid - off] : 0;
        __syncthreads();
        x += y; buf[tid] = x;
        __syncthreads();
    }
    int run = t*E_EDGES + (x - s);
    offs[t*1024 + tid] = run;
    counts[t*1024 + tid] = s;
    #pragma unroll
    for (int j = 0; j < NBLK; j++){
        bh[base + j] = run;
        run += vals[j];
    }
}

// ================= scatter ===================================================
__global__ __launch_bounds__(256) void scatter_kernel(const int* __restrict__ receivers,
                                                      const int* __restrict__ senders,
                                                      const int* __restrict__ bh,
                                                      int* __restrict__ sorted){
    int hb = blockIdx.x, t = hb >> 4, blk = hb & 15;
    int tid = threadIdx.x;
    __shared__ int cur[1024];
    for (int bin = tid; bin < 1024; bin += 256) cur[bin] = bh[(t*1024 + bin)*NBLK + blk];
    __syncthreads();
    long base = (long)(t+1)*E_EDGES + blk*8192;
    #pragma unroll 2
    for (int it = 0; it < 32; it++){
        int e = blk*8192 + it*256 + tid;
        int r = receivers[base + it*256 + tid];
        int snd = senders[base + it*256 + tid];
        int pos = atomicAdd(&cur[r], 1);
        sorted[pos] = e | (snd << 17);
    }
}

// ================= edge kernel: ZERO-LDS, ZERO-BARRIER =======================
// MFMA A-fragments are loaded DIRECTLY from global (lane l <-> row l&15,
// k = f*32 + (l>>4)*8 + j), converted in-register with v_cvt_pk_bf16_f32
// (RNE, same as f2bf_rne). Per-edge metadata (sender id, dirs) distributed
// via __shfl. No __syncthreads anywhere: all 4 waves of a block (and all
// blocks on a CU) are fully independent -> latency hidden by TLP, and the
// compiler can pipeline freely across iterations (no stores in the loop).
__global__ __launch_bounds__(256) void edge_kernel(
    const float* __restrict__ dist, const float* __restrict__ dirs,
    const ushort_t* __restrict__ tabA, const ushort_t* __restrict__ tabB,
    const short* __restrict__ fragH, const short* __restrict__ fragL,
    const int* __restrict__ counts, const int* __restrict__ offs, const int* __restrict__ sorted,
    float* __restrict__ zbuf)
{
    int b = blockIdx.x;
    int t = b >> 10, node = b & 1023;
    const ushort_t* ta = tabA + ((t == 0) ? 0 : (t == 1 ? 32768 : 163840));
    const ushort_t* tb = tabB + ((t == 0) ? 0 : (t == 1 ? 65536 : 327680));
    const float* dbase = dist + (long)(t+1)*E_EDGES*64;
    const float* dirbase = dirs + (long)(t+1)*E_EDGES*3;

    int tid = threadIdx.x;
    int w = tid >> 6, l = tid & 63;
    int q = l >> 4, c16 = l & 15;
    int d = w*16 + c16;           // output dim for gather tables / zbuf

    // B fragments (W_w hi/lo) in registers: wave w -> col tiles {w, w+4, w+8}
    short8 bhf[3][2], blf[3][2];
    #pragma unroll
    for (int ni = 0; ni < 3; ni++){
        int nt = w + ni*4;
        #pragma unroll
        for (int ks = 0; ks < 2; ks++){
            long base = (long)t*12288 + ((nt*2 + ks)*64 + l)*8;
            bhf[ni][ks] = *(const short8*)(fragH + base);
            blf[ni][ks] = *(const short8*)(fragL + base);
        }
    }

    float acc_s = 0.f, acc_v0 = 0.f, acc_v1 = 0.f, acc_v2 = 0.f;

    int deg   = counts[t*1024 + node];
    int start = offs[t*1024 + node];

    const float4_t z4 = {0.f,0.f,0.f,0.f};

    for (int e0 = 0; e0 < deg; e0 += 16){
        int rem = deg - e0;
        // own A-row edge (clamped for the ragged tail; masked in epilogue)
        int ridx = (c16 < rem) ? c16 : 0;
        int sA = sorted[(long)start + e0 + ridx];
        long eA = (long)(sA & 131071);
        const float* dp = dbase + eA*64 + q*8;
        float8_t f0 = *(const float8_t*)(dp);        // k in [q*8, q*8+8)
        float8_t f1 = *(const float8_t*)(dp + 32);   // k in [32+q*8, ...)
        float dir0 = dirbase[eA*3 + 0];
        float dir1 = dirbase[eA*3 + 1];
        float dir2 = dirbase[eA*3 + 2];

        // convert A to bf16 hi/lo (packed RNE converts, bit-identical to f2bf_rne)
        union { int4_t i; short8 s; } H0, L0, H1, L1;
        #pragma unroll
        for (int j = 0; j < 4; j++){
            float a0 = f0[2*j], a1 = f0[2*j+1];
            uint32_t hp, lp;
            asm("v_cvt_pk_bf16_f32 %0, %1, %2" : "=v"(hp) : "v"(a0), "v"(a1));
            float r0 = asf_lo(hp), r1 = asf_hi(hp);
            asm("v_cvt_pk_bf16_f32 %0, %1, %2" : "=v"(lp) : "v"(a0 - r0), "v"(a1 - r1));
            H0.i[j] = (int)hp; L0.i[j] = (int)lp;
            float b0 = f1[2*j], b1 = f1[2*j+1];
            uint32_t hq, lq;
            asm("v_cvt_pk_bf16_f32 %0, %1, %2" : "=v"(hq) : "v"(b0), "v"(b1));
            float s0 = asf_lo(hq), s1 = asf_hi(hq);
            asm("v_cvt_pk_bf16_f32 %0, %1, %2" : "=v"(lq) : "v"(b0 - s0), "v"(b1 - s1));
            H1.i[j] = (int)hq; L1.i[j] = (int)lq;
        }
        short8 ah0 = H0.s, al0 = L0.s, ah1 = H1.s, al1 = L1.s;

        // epilogue metadata for this lane's 4 C-rows (edges q*4+r) via shuffle
        uint32_t gA[4]; uint2_t gB[4];
        float dls0[4], dls1[4], dls2[4];
        #pragma unroll
        for (int r = 0; r < 4; r++){
            int srcl = q*4 + r;
            int sr = __shfl(sA, srcl);
            int s = ((unsigned)sr) >> 17;
            gA[r] = *(const uint32_t*)(ta + (long)(s*64 + d)*2);
            gB[r] = *(const uint2_t*)(tb + (long)(s*64 + d)*4);
            dls0[r] = __shfl(dir0, srcl);
            dls1[r] = __shfl(dir1, srcl);
            dls2[r] = __shfl(dir2, srcl);
        }

        // MFMA: we = dist @ W_w, split-bf16 3-term (same order as before)
        float4_t C[3];
        #pragma unroll
        for (int ni = 0; ni < 3; ni++){
            float4_t acc = z4;
            acc = __builtin_amdgcn_mfma_f32_16x16x32_bf16(ah0, bhf[ni][0], acc, 0, 0, 0);
            acc = __builtin_amdgcn_mfma_f32_16x16x32_bf16(ah1, bhf[ni][1], acc, 0, 0, 0);
            acc = __builtin_amdgcn_mfma_f32_16x16x32_bf16(ah0, blf[ni][0], acc, 0, 0, 0);
            acc = __builtin_amdgcn_mfma_f32_16x16x32_bf16(ah1, blf[ni][1], acc, 0, 0, 0);
            acc = __builtin_amdgcn_mfma_f32_16x16x32_bf16(al0, bhf[ni][0], acc, 0, 0, 0);
            acc = __builtin_amdgcn_mfma_f32_16x16x32_bf16(al1, bhf[ni][1], acc, 0, 0, 0);
            C[ni] = acc;
        }

        // epilogue: phi = we*hx folded via bf16 gather tables (ragged-masked)
        #pragma unroll
        for (int r = 0; r < 4; r++){
            bool ok = (q*4 + r) < rem;
            float hs  = ok ? asf_lo(gA[r]) : 0.f;
            float hvs = ok ? asf_hi(gA[r]) : 0.f;
            float hv0 = ok ? asf_lo(gB[r][0]) : 0.f;
            float hv1 = ok ? asf_hi(gB[r][0]) : 0.f;
            float hv2 = ok ? asf_lo(gB[r][1]) : 0.f;
            acc_s += C[0][r] * hs;
            float pvs = C[2][r] * hvs;
            acc_v0 += C[1][r]*hv0 + pvs * dls0[r];
            acc_v1 += C[1][r]*hv1 + pvs * dls1[r];
            acc_v2 += C[1][r]*hv2 + pvs * dls2[r];
        }
    }

    // cross-quad reduction (C rows live in different quads)
    acc_s  += __shfl_xor(acc_s, 16);  acc_s  += __shfl_xor(acc_s, 32);
    acc_v0 += __shfl_xor(acc_v0, 16); acc_v0 += __shfl_xor(acc_v0, 32);
    acc_v1 += __shfl_xor(acc_v1, 16); acc_v1 += __shfl_xor(acc_v1, 32);
    acc_v2 += __shfl_xor(acc_v2, 16); acc_v2 += __shfl_xor(acc_v2, 32);
    if (l < 16){
        float* zp = zbuf + ((long)(t*1024 + node))*256;
        zp[d] = acc_s;
        zp[64 + d*3 + 0] = acc_v0;
        zp[64 + d*3 + 1] = acc_v1;
        zp[64 + d*3 + 2] = acc_v2;
    }
}

// ================= batched node update: block = (type, 4 nodes) ==============
__global__ __launch_bounds__(256) void update_kernel(
    const float* __restrict__ W_V, const float* __restrict__ W_U,
    const float* __restrict__ W_g1, const float* __restrict__ W_g2,
    const float* __restrict__ zbuf, float* __restrict__ out)
{
    int b = blockIdx.x;
    int t = b >> 8, tp = t + 1;
    int nb = (b & 255) * UNPB;
    int tid = threadIdx.x;

    __shared__ float zls[UNPB][256];
    __shared__ float Vv[UNPB][64][3], Uv[UNPB][64][3];
    __shared__ float gin[UNPB][128];
    __shared__ float hid[UNPB][128];
    __shared__ float aL[UNPB][192];
    __shared__ float vdot[UNPB][64];

    {   // load z: UNPB*256 floats, one float4 per thread
        int n = tid >> 6, c = tid & 63;
        *(float4_t*)&zls[n][c*4] =
            *(const float4_t*)(zbuf + ((long)(t*1024 + nb + n))*256 + c*4);
    }
    __syncthreads();

    {   // Vv/Uv: thread = (node n, feature f); zls broadcast across wave
        int f = tid & 63, n = tid >> 6;
        const float* wv = W_V + (long)tp*4096;
        const float* wu = W_U + (long)tp*4096;
        float av0=0,av1=0,av2=0,au0=0,au1=0,au2=0;
        #pragma unroll 4
        for (int dd = 0; dd < 64; dd++){
            float wvv = wv[dd*64 + f], wuu = wu[dd*64 + f];
            float z0 = zls[n][64 + dd*3 + 0];
            float z1 = zls[n][64 + dd*3 + 1];
            float z2 = zls[n][64 + dd*3 + 2];
            av0 += z0*wvv; av1 += z1*wvv; av2 += z2*wvv;
            au0 += z0*wuu; au1 += z1*wuu; au2 += z2*wuu;
        }
        Vv[n][f][0]=av0; Vv[n][f][1]=av1; Vv[n][f][2]=av2;
        Uv[n][f][0]=au0; Uv[n][f][1]=au1; Uv[n][f][2]=au2;
    }
    __syncthreads();

    {   // gin + vdot
        int n = tid >> 6, f = tid & 63;
        float v0=Vv[n][f][0], v1=Vv[n][f][1], v2=Vv[n][f][2];
        float u0=Uv[n][f][0], u1=Uv[n][f][1], u2=Uv[n][f][2];
        gin[n][f]      = zls[n][f];
        gin[n][64 + f] = v0*v0 + v1*v1 + v2*v2;
        vdot[n][f]     = u0*v0 + u1*v1 + u2*v2;
    }
    __syncthreads();

    {   // g1: 128 hidden cols x 2 node-groups
        int h = tid & 127, ng = tid >> 7;
        const float* w1 = W_g1 + (long)tp*16384;
        float a0=0, a1=0;
        #pragma unroll 4
        for (int c = 0; c < 128; c++){
            float w = w1[c*128 + h];
            a0 += gin[ng*2+0][c]*w;
            a1 += gin[ng*2+1][c]*w;
        }
        hid[ng*2+0][h] = silu_f(a0);
        hid[ng*2+1][h] = silu_f(a1);
    }
    __syncthreads();

    if (tid < 192){   // g2: 192 cols, 4 nodes each
        const float* w2 = W_g2 + (long)tp*24576;
        float a0=0,a1=0,a2=0,a3=0;
        #pragma unroll 4
        for (int h = 0; h < 128; h++){
            float w = w2[h*192 + tid];
            a0 += hid[0][h]*w; a1 += hid[1][h]*w;
            a2 += hid[2][h]*w; a3 += hid[3][h]*w;
        }
        aL[0][tid]=a0; aL[1][tid]=a1; aL[2][tid]=a2; aL[3][tid]=a3;
    }
    __syncthreads();

    {   // scalar + vector update
        int n = tid >> 6, f = tid & 63;
        float upd = aL[n][128 + f]*vdot[n][f] + aL[n][f];
        atomicAdd(&out[(nb + n)*256 + f], upd);
        float g = aL[n][64 + f];
        #pragma unroll
        for (int i = 0; i < 3; i++){
            float updv = Uv[n][f][i] * g;
            atomicAdd(&out[(nb + n)*256 + 64 + f*3 + i], updv);
        }
    }
}

// ================= fused fallback (previous proven kernel) ===================
__global__ __launch_bounds__(256) void main_kernel(
    const float* __restrict__ dist, const float* __restrict__ dirs,
    const float* __restrict__ W_V, const float* __restrict__ W_U,
    const float* __restrict__ W_g1, const float* __restrict__ W_g2,
    const ushort_t* __restrict__ tabA, const ushort_t* __restrict__ tabB,
    const short* __restrict__ fragH, const short* __restrict__ fragL,
    const int* __restrict__ counts, const int* __restrict__ offs, const int* __restrict__ sorted,
    float* __restrict__ out)
{
    int b = blockIdx.x;
    int t = b >> 10, node = b & 1023, tp = t + 1;
    const ushort_t* ta = tabA + ((t == 0) ? 0 : (t == 1 ? 32768 : 163840));
    const ushort_t* tb = tabB + ((t == 0) ? 0 : (t == 1 ? 65536 : 327680));
    const float* dbase = dist + (long)tp*E_EDGES*64;
    const float* dirbase = dirs + (long)tp*E_EDGES*3;

    int tid = threadIdx.x;
    int w = tid >> 6, l = tid & 63;
    int q = l >> 4, c16 = l & 15;
    int d = w*16 + c16;

    __shared__ short AH[2][2][64][8];
    __shared__ short AL[2][2][64][8];
    __shared__ float dls[2][16][3];
    __shared__ int eid[MAXCHUNK];
    __shared__ int sid[MAXCHUNK];
    __shared__ float zs[64];
    __shared__ float zv[64][3];
    __shared__ float VvL[192], UvL[192];
    __shared__ float gin[128], hidl[128], aLrr[192], vdotL[64];

    short8 bhf[3][2], blf[3][2];
    #pragma unroll
    for (int ni = 0; ni < 3; ni++){
        int nt = w + ni*4;
        #pragma unroll
        for (int ks = 0; ks < 2; ks++){
            long base = (long)t*12288 + ((nt*2 + ks)*64 + l)*8;
            bhf[ni][ks] = *(const short8*)(fragH + base);
            blf[ni][ks] = *(const short8*)(fragL + base);
        }
    }

    float acc_s = 0.f, acc_v0 = 0.f, acc_v1 = 0.f, acc_v2 = 0.f;

    int deg   = counts[t*1024 + node];
    int start = offs[t*1024 + node];

    int m = tid >> 4, seg = tid & 15;
    int ks_w = seg >> 3, quad_w = (seg >> 1) & 3, j0_w = (seg & 1)*4;
    int lane2 = m | (quad_w << 4);
    int mm = tid / 3, ii = tid - mm*3;

    const float4_t z4 = {0.f,0.f,0.f,0.f};

    for (int cbase = 0; cbase < deg; cbase += MAXCHUNK){
        int chunk = deg - cbase; if (chunk > MAXCHUNK) chunk = MAXCHUNK;
        __syncthreads();
        {
            int v = 0;
            if (tid < chunk) v = sorted[(long)start + cbase + tid];
            eid[tid] = v & 131071;
            sid[tid] = ((unsigned)v) >> 17;
        }
        __syncthreads();

        int ngroups = (chunk + 15) >> 4;
        float4_t dv = z4;
        if (m < chunk) dv = *(const float4_t*)(dbase + (long)eid[m]*64 + seg*4);
        float dirv = 0.f;
        if (tid < 48 && mm < chunk) dirv = dirbase[(long)eid[mm]*3 + ii];
        uint32_t gA[4]; uint2_t gB[4];
        #pragma unroll
        for (int r = 0; r < 4; r++){
            int s = sid[q*4 + r];
            gA[r] = *(const uint32_t*)(ta + (long)(s*64 + d)*2);
            gB[r] = *(const uint2_t*)(tb + (long)(s*64 + d)*4);
        }

        for (int g = 0; g < ngroups; g++){
            int buf = g & 1;
            {
                short4_t h4, l4;
                #pragma unroll
                for (int jj = 0; jj < 4; jj++){
                    short hi = f2bf_rne(dv[jj]);
                    h4[jj] = hi;
                    l4[jj] = f2bf_rne(dv[jj] - bf2f(hi));
                }
                *(short4_t*)&AH[buf][ks_w][lane2][j0_w] = h4;
                *(short4_t*)&AL[buf][ks_w][lane2][j0_w] = l4;
                if (tid < 48) dls[buf][mm][ii] = dirv;
            }
            float4_t dvn = z4; float dirn = 0.f;
            uint32_t gAn[4] = {0,0,0,0}; uint2_t gBn[4] = {{0,0},{0,0},{0,0},{0,0}};
            if (g + 1 < ngroups){
                int li = (g+1)*16 + m;
                if (li < chunk) dvn = *(const float4_t*)(dbase + (long)eid[li]*64 + seg*4);
                int li2 = (g+1)*16 + mm;
                if (tid < 48 && li2 < chunk) dirn = dirbase[(long)eid[li2]*3 + ii];
                #pragma unroll
                for (int r = 0; r < 4; r++){
                    int s = sid[(g+1)*16 + q*4 + r];
                    gAn[r] = *(const uint32_t*)(ta + (long)(s*64 + d)*2);
                    gBn[r] = *(const uint2_t*)(tb + (long)(s*64 + d)*4);
                }
            }
            __syncthreads();

            short8 ah0 = *(short8*)&AH[buf][0][l][0];
            short8 ah1 = *(short8*)&AH[buf][1][l][0];
            short8 al0 = *(short8*)&AL[buf][0][l][0];
            short8 al1 = *(short8*)&AL[buf][1][l][0];
            float4_t C[3];
            #pragma unroll
            for (int ni = 0; ni < 3; ni++){
                float4_t acc = z4;
                acc = __builtin_amdgcn_mfma_f32_16x16x32_bf16(ah0, bhf[ni][0], acc, 0, 0, 0);
                acc = __builtin_amdgcn_mfma_f32_16x16x32_bf16(ah1, bhf[ni][1], acc, 0, 0, 0);
                acc = __builtin_amdgcn_mfma_f32_16x16x32_bf16(ah0, blf[ni][0], acc, 0, 0, 0);
                acc = __builtin_amdgcn_mfma_f32_16x16x32_bf16(ah1, blf[ni][1], acc, 0, 0, 0);
                acc = __builtin_amdgcn_mfma_f32_16x16x32_bf16(al0, bhf[ni][0], acc, 0, 0, 0);
                acc = __builtin_amdgcn_mfma_f32_16x16x32_bf16(al1, bhf[ni][1], acc, 0, 0, 0);
                C[ni] = acc;
            }

            #pragma unroll
            for (int r = 0; r < 4; r++){
                int mr = q*4 + r;
                float hs  = asf_lo(gA[r]);
                float hvs = asf_hi(gA[r]);
                float hv0 = asf_lo(gB[r][0]);
                float hv1 = asf_hi(gB[r][0]);
                float hv2 = asf_lo(gB[r][1]);
                acc_s += C[0][r] * hs;
                float pvs = C[2][r] * hvs;
                acc_v0 += C[1][r]*hv0 + pvs * dls[buf][mr][0];
                acc_v1 += C[1][r]*hv1 + pvs * dls[buf][mr][1];
                acc_v2 += C[1][r]*hv2 + pvs * dls[buf][mr][2];
            }
            dv = dvn; dirv = dirn;
            #pragma unroll
            for (int r = 0; r < 4; r++){ gA[r] = gAn[r]; gB[r] = gBn[r]; }
        }
    }

    acc_s  += __shfl_xor(acc_s, 16);  acc_s  += __shfl_xor(acc_s, 32);
    acc_v0 += __shfl_xor(acc_v0, 16); acc_v0 += __shfl_xor(acc_v0, 32);
    acc_v1 += __shfl_xor(acc_v1, 16); acc_v1 += __shfl_xor(acc_v1, 32);
    acc_v2 += __shfl_xor(acc_v2, 16); acc_v2 += __shfl_xor(acc_v2, 32);
    __syncthreads();
    if (l < 16){
        zs[d] = acc_s;
        zv[d][0] = acc_v0; zv[d][1] = acc_v1; zv[d][2] = acc_v2;
    }
    __syncthreads();

    if (tid < 192){
        int i = tid >> 6, f = tid & 63;
        const float* wv = W_V + (long)tp*64*64;
        const float* wu = W_U + (long)tp*64*64;
        float av = 0.f, au = 0.f;
        #pragma unroll 8
        for (int dd = 0; dd < 64; dd++){
            float z = zv[dd][i];
            av += z * wv[dd*64 + f];
            au += z * wu[dd*64 + f];
        }
        VvL[f*3 + i] = av;
        UvL[f*3 + i] = au;
    }
    __syncthreads();
    if (tid < 64){
        int f = tid;
        float v0 = VvL[f*3], v1 = VvL[f*3+1], v2 = VvL[f*3+2];
        float u0 = UvL[f*3], u1 = UvL[f*3+1], u2 = UvL[f*3+2];
        gin[f] = zs[f];
        gin[64 + f] = v0*v0 + v1*v1 + v2*v2;
        vdotL[f] = u0*v0 + u1*v1 + u2*v2;
    }
    __syncthreads();
    if (tid < 128){
        const float* w1 = W_g1 + (long)tp*128*128;
        float acc = 0.f;
        #pragma unroll 8
        for (int c = 0; c < 128; c++) acc += gin[c] * w1[c*128 + tid];
        hidl[tid] = silu_f(acc);
    }
    __syncthreads();
    if (tid < 192){
        const float* w2 = W_g2 + (long)tp*128*192;
        float acc = 0.f;
        #pragma unroll 8
        for (int h = 0; h < 128; h++) acc += hidl[h] * w2[h*192 + tid];
        aLrr[tid] = acc;
    }
    __syncthreads();
    if (tid < 64){
        int f = tid;
        float upd = aLrr[128 + f] * vdotL[f] + aLrr[f];
        atomicAdd(&out[node*256 + f], upd);
    }
    if (tid < 192){
        int i = tid >> 6, f = tid & 63;
        float updv = UvL[f*3 + i] * aLrr[64 + f];
        atomicAdd(&out[node*256 + 64 + f*3 + i], updv);
    }
}

// ================= launcher ==================================================
extern "C" void kernel_launch(void* const* d_in, const int* in_sizes, int n_in,
                              void* d_out, int out_size, void* d_ws, size_t ws_size,
                              hipStream_t stream){
    const float* s_elec  = (const float*)d_in[0];
    const float* v_elec  = (const float*)d_in[1];
    const float* s_nuc   = (const float*)d_in[2];
    const float* v_nuc   = (const float*)d_in[3];
    const float* dist    = (const float*)d_in[4];
    const float* dirs    = (const float*)d_in[5];
    const float* W_w     = (const float*)d_in[6];
    const float* W_h1    = (const float*)d_in[7];
    const float* W_h2    = (const float*)d_in[8];
    const float* W_g1    = (const float*)d_in[9];
    const float* W_g2    = (const float*)d_in[10];
    const float* W_V     = (const float*)d_in[11];
    const float* W_U     = (const float*)d_in[12];
    const int* senders   = (const int*)d_in[13];
    const int* receivers = (const int*)d_in[14];
    float* out = (float*)d_out;
    char* ws = (char*)d_ws;

    // workspace layout (bytes)
    ushort_t* tabA  = (ushort_t*)(ws + 0);        // 589824 B  (h_s, h_vs) bf16
    ushort_t* tabB  = (ushort_t*)(ws + 589824);   // 1179648 B (hv0,hv1,hv2,pad) bf16
    short* fragH  = (short*)(ws + 1769472);       // 73728 B
    short* fragL  = (short*)(ws + 1843200);       // 73728 B
    int*   bh     = (int*)  (ws + 1916928);       // 196608 B
    int*   offs   = (int*)  (ws + 2113536);       // 12288 B
    int*   counts = (int*)  (ws + 2125824);       // 12288 B
    int*   sorted = (int*)  (ws + 2138112);       // 1572864 B -> end 3710976
    float* zbuf   = (float*)(ws + 3710976);       // 3145728 B -> end 6856704
    if (ws_size < 3710976) return;
    bool split = (ws_size >= 6856704);

    prep_kernel<<<dim3(595), dim3(256), 0, stream>>>(
        s_elec, v_elec, s_nuc, v_nuc, W_h1, W_h2, W_w, receivers,
        tabA, tabB, fragH, fragL, bh, out);
    scan_kernel<<<dim3(3), dim3(1024), 0, stream>>>(bh, offs, counts);
    scatter_kernel<<<dim3(48), dim3(256), 0, stream>>>(receivers, senders, bh, sorted);
    if (split){
        edge_kernel<<<dim3(3072), dim3(256), 0, stream>>>(
            dist, dirs, tabA, tabB, fragH, fragL, counts, offs, sorted, zbuf);
        update_kernel<<<dim3(768), dim3(256), 0, stream>>>(
            W_V, W_U, W_g1, W_g2, zbuf, out);
    } else {
        main_kernel<<<dim3(3072), dim3(256), 0, stream>>>(
            dist, dirs, W_V, W_U, W_g1, W_g2,
            tabA, tabB, fragH, fragL, counts, offs, sorted, out);
    }
}

// Round 5
// 332.574 us; speedup vs baseline: 1.1913x; 1.1913x over previous
//
#include <hip/hip_runtime.h>
#include <stdint.h>

#define E_EDGES 131072
#define NELEC 1024
#define NNUC 256
#define MAXCHUNK 256
#define NBLK 16          // hist/scatter blocks per type
#define UNPB 4           // nodes per update block

typedef unsigned short ushort_t;
typedef __attribute__((ext_vector_type(8))) short short8;
typedef __attribute__((ext_vector_type(4))) short short4_t;
typedef __attribute__((ext_vector_type(4))) float float4_t;
typedef __attribute__((ext_vector_type(8))) float float8_t;
typedef __attribute__((ext_vector_type(4))) int int4_t;
typedef __attribute__((ext_vector_type(2))) unsigned int uint2_t;

__device__ inline float silu_f(float x){ return x / (1.0f + expf(-x)); }

__device__ inline short f2bf_rne(float x){
    union { float f; uint32_t u; } a; a.f = x;
    return (short)((a.u + 0x7fffu + ((a.u >> 16) & 1u)) >> 16);
}
__device__ inline float bf2f(short h){
    union { uint32_t u; float f; } a; a.u = ((uint32_t)(uint16_t)h) << 16;
    return a.f;
}
__device__ inline ushort_t bfu(float x){ return (ushort_t)f2bf_rne(x); }
__device__ inline float asf_lo(uint32_t u){ union { uint32_t u; float f; } a; a.u = u << 16; return a.f; }
__device__ inline float asf_hi(uint32_t u){ union { uint32_t u; float f; } a; a.u = u & 0xFFFF0000u; return a.f; }

// ================= prep: gather tables + W_w swizzle + out-init + histogram ==
__global__ __launch_bounds__(256) void prep_kernel(
    const float* __restrict__ s_elec, const float* __restrict__ v_elec,
    const float* __restrict__ s_nuc,  const float* __restrict__ v_nuc,
    const float* __restrict__ W_h1, const float* __restrict__ W_h2,
    const float* __restrict__ W_w,
    const int* __restrict__ receivers,
    ushort_t* __restrict__ tabA, ushort_t* __restrict__ tabB,
    short* __restrict__ fragH, short* __restrict__ fragL,
    int* __restrict__ bh, float* __restrict__ out)
{
    int b = blockIdx.x, tid = threadIdx.x;
    __shared__ float sls[8][64];
    __shared__ float hidls[128][8];
    __shared__ int hist[1024];

    if (b < 288){
        int t, node0;
        if (b < 32){ t = 0; node0 = b*8; }
        else if (b < 160){ t = 1; node0 = (b-32)*8; }
        else { t = 2; node0 = (b-160)*8; }
        int tp = t + 1;
        const float* src = (t == 0) ? s_nuc : s_elec;
        const float* vsrc = (t == 0) ? v_nuc : v_elec;
        long baseA = (t == 0) ? 0 : (t == 1 ? 32768 : 163840);
        long baseB = (t == 0) ? 0 : (t == 1 ? 65536 : 327680);
        for (int i = tid; i < 512; i += 256){ int n = i >> 6, f = i & 63; sls[n][f] = src[(node0+n)*64 + f]; }
        __syncthreads();
        {
            int j = tid & 127, nh = tid >> 7;
            const float* w1 = W_h1 + (long)tp*64*128;
            float a0=0,a1=0,a2=0,a3=0;
            #pragma unroll 8
            for (int f = 0; f < 64; f++){
                float w = w1[f*128 + j];
                a0 += sls[nh*4+0][f]*w; a1 += sls[nh*4+1][f]*w;
                a2 += sls[nh*4+2][f]*w; a3 += sls[nh*4+3][f]*w;
            }
            float4_t hv = { silu_f(a0), silu_f(a1), silu_f(a2), silu_f(a3) };
            *(float4_t*)&hidls[j][nh*4] = hv;
        }
        __syncthreads();
        if (tid < 192){
            const float* w2 = W_h2 + (long)tp*128*192;
            float acc[8] = {0,0,0,0,0,0,0,0};
            #pragma unroll 4
            for (int h = 0; h < 128; h++){
                float w = w2[h*192 + tid];
                float4_t ha = *(float4_t*)&hidls[h][0];
                float4_t hb = *(float4_t*)&hidls[h][4];
                acc[0]+=ha[0]*w; acc[1]+=ha[1]*w; acc[2]+=ha[2]*w; acc[3]+=ha[3]*w;
                acc[4]+=hb[0]*w; acc[5]+=hb[1]*w; acc[6]+=hb[2]*w; acc[7]+=hb[3]*w;
            }
            int p = tid >> 6, d2 = tid & 63;
            if (p == 0){
                #pragma unroll
                for (int n = 0; n < 8; n++)
                    tabA[baseA + (long)((node0+n)*64 + d2)*2 + 0] = bfu(acc[n]);
            } else if (p == 2){
                #pragma unroll
                for (int n = 0; n < 8; n++)
                    tabA[baseA + (long)((node0+n)*64 + d2)*2 + 1] = bfu(acc[n]);
            } else {
                #pragma unroll
                for (int n = 0; n < 8; n++){
                    const float* vp = vsrc + (long)(node0+n)*192 + d2*3;
                    long o = baseB + (long)((node0+n)*64 + d2)*4;
                    tabB[o+0] = bfu(acc[n]*vp[0]);
                    tabB[o+1] = bfu(acc[n]*vp[1]);
                    tabB[o+2] = bfu(acc[n]*vp[2]);
                }
            }
        }
    } else if (b < 291){
        int t = b - 288, tp = t + 1;
        const float* W = W_w + (long)tp*64*192;
        for (int idx = tid; idx < 12288; idx += 256){
            int j    = idx & 7;
            int lane = (idx >> 3) & 63;
            int ks   = (idx >> 9) & 1;
            int nt   = idx >> 10;
            int k = ks*32 + ((lane >> 4) & 3)*8 + j;
            int n = nt*16 + (lane & 15);
            float v = W[k*192 + n];
            short hi = f2bf_rne(v);
            short lo = f2bf_rne(v - bf2f(hi));
            fragH[t*12288 + idx] = hi;
            fragL[t*12288 + idx] = lo;
        }
    } else if (b < 547){
        int i = (b - 291)*256 + tid;
        int n = i >> 6, c4 = i & 63;
        float4_t v;
        if (c4 < 16) v = *(const float4_t*)(s_elec + n*64 + c4*4);
        else         v = *(const float4_t*)(v_elec + n*192 + (c4-16)*4);
        *(float4_t*)(out + n*256 + c4*4) = v;
    } else {
        int hb = b - 547, t = hb >> 4, blk = hb & 15;
        for (int i = tid; i < 1024; i += 256) hist[i] = 0;
        __syncthreads();
        long base = (long)(t+1)*E_EDGES + blk*8192;
        #pragma unroll 4
        for (int it = 0; it < 32; it++){
            int r = receivers[base + it*256 + tid];
            atomicAdd(&hist[r], 1);
        }
        __syncthreads();
        for (int bin = tid; bin < 1024; bin += 256)
            bh[(t*1024 + bin)*NBLK + blk] = hist[bin];
    }
}

// ================= scan ======================================================
__global__ __launch_bounds__(1024) void scan_kernel(int* __restrict__ bh,
                                                    int* __restrict__ offs,
                                                    int* __restrict__ counts){
    __shared__ int buf[1024];
    int t = blockIdx.x;
    int tid = threadIdx.x;
    int base = (t*1024 + tid)*NBLK;
    int vals[NBLK];
    const int4_t* p = (const int4_t*)(bh + base);
    int s = 0;
    #pragma unroll
    for (int j = 0; j < NBLK/4; j++){
        int4_t x = p[j];
        vals[j*4+0]=x[0]; vals[j*4+1]=x[1]; vals[j*4+2]=x[2]; vals[j*4+3]=x[3];
        s += x[0]+x[1]+x[2]+x[3];
    }
    buf[tid] = s;
    __syncthreads();
    int x = s;
    for (int off = 1; off < 1024; off <<= 1){
        int y = (tid >= off) ? buf[tid - off] : 0;
        __syncthreads();
        x += y; buf[tid] = x;
        __syncthreads();
    }
    int run = t*E_EDGES + (x - s);
    offs[t*1024 + tid] = run;
    counts[t*1024 + tid] = s;
    #pragma unroll
    for (int j = 0; j < NBLK; j++){
        bh[base + j] = run;
        run += vals[j];
    }
}

// ================= scatter ===================================================
__global__ __launch_bounds__(256) void scatter_kernel(const int* __restrict__ receivers,
                                                      const int* __restrict__ senders,
                                                      const int* __restrict__ bh,
                                                      int* __restrict__ sorted){
    int hb = blockIdx.x, t = hb >> 4, blk = hb & 15;
    int tid = threadIdx.x;
    __shared__ int cur[1024];
    for (int bin = tid; bin < 1024; bin += 256) cur[bin] = bh[(t*1024 + bin)*NBLK + blk];
    __syncthreads();
    long base = (long)(t+1)*E_EDGES + blk*8192;
    #pragma unroll 2
    for (int it = 0; it < 32; it++){
        int e = blk*8192 + it*256 + tid;
        int r = receivers[base + it*256 + tid];
        int snd = senders[base + it*256 + tid];
        int pos = atomicAdd(&cur[r], 1);
        sorted[pos] = e | (snd << 17);
    }
}

// ================= edge kernel: R1 schedule + R2 conflict-free staging =======
// 32-edge supergroups: 256 threads each load one float8 of a dist row (8
// consecutive lanes cover a full 256B row), convert with v_cvt_pk_bf16_f32,
// and issue ONE ds_write_b128 each for hi/lo at XOR-swizzled slots (pattern
// measured 0 conflicts in R2). Next supergroup's dist rows + rolling depth-1
// tab gathers are prefetched into registers and stay in flight across the
// barrier (R1-proven). 1 barrier per 32 edges.
__global__ __launch_bounds__(256) void edge_kernel(
    const float* __restrict__ dist, const float* __restrict__ dirs,
    const ushort_t* __restrict__ tabA, const ushort_t* __restrict__ tabB,
    const short* __restrict__ fragH, const short* __restrict__ fragL,
    const int* __restrict__ counts, const int* __restrict__ offs, const int* __restrict__ sorted,
    float* __restrict__ zbuf)
{
    int b = blockIdx.x;
    int t = b >> 10, node = b & 1023;
    const ushort_t* ta = tabA + ((t == 0) ? 0 : (t == 1 ? 32768 : 163840));
    const ushort_t* tb = tabB + ((t == 0) ? 0 : (t == 1 ? 65536 : 327680));
    const float* dbase = dist + (long)(t+1)*E_EDGES*64;
    const float* dirbase = dirs + (long)(t+1)*E_EDGES*3;

    int tid = threadIdx.x;
    int w = tid >> 6, l = tid & 63;
    int q = l >> 4, c16 = l & 15;
    int d = w*16 + c16;                 // output dim for gather tables / zbuf
    int srow = tid >> 3, seg8 = tid & 7; // staging: row (0..31), 8-feat segment
    int mm = tid / 3, ii = tid - mm*3;   // dirs staging roles (tid<96)

    // A supergroup tile: 32 rows x 8 slots x 16B, slot = seg8 ^ (row&7)
    __shared__ __attribute__((aligned(16))) short AHs[2][2048];
    __shared__ __attribute__((aligned(16))) short ALs[2][2048];
    __shared__ float dls[2][32][3];
    __shared__ int eid[MAXCHUNK];
    __shared__ int sid[MAXCHUNK];

    // B fragments (W_w hi/lo) in registers: wave w -> col tiles {w, w+4, w+8}
    short8 bhf[3][2], blf[3][2];
    #pragma unroll
    for (int ni = 0; ni < 3; ni++){
        int nt = w + ni*4;
        #pragma unroll
        for (int ks = 0; ks < 2; ks++){
            long base = (long)t*12288 + ((nt*2 + ks)*64 + l)*8;
            bhf[ni][ks] = *(const short8*)(fragH + base);
            blf[ni][ks] = *(const short8*)(fragL + base);
        }
    }

    float acc_s = 0.f, acc_v0 = 0.f, acc_v1 = 0.f, acc_v2 = 0.f;

    int deg   = counts[t*1024 + node];
    int start = offs[t*1024 + node];

    const float4_t z4 = {0.f,0.f,0.f,0.f};
    const float8_t z8 = {0.f,0.f,0.f,0.f,0.f,0.f,0.f,0.f};

    for (int cbase = 0; cbase < deg; cbase += MAXCHUNK){
        int chunk = deg - cbase; if (chunk > MAXCHUNK) chunk = MAXCHUNK;
        __syncthreads();   // previous chunk's eid/sid readers done
        {
            int v = 0;
            if (tid < chunk) v = sorted[(long)start + cbase + tid];
            eid[tid] = v & 131071;
            sid[tid] = ((unsigned)v) >> 17;
        }
        __syncthreads();

        int nsg = (chunk + 31) >> 5;
        int ngroups = (chunk + 15) >> 4;

        // prologue: supergroup 0 dist rows + dirs into registers
        float8_t f8 = z8; float dirv = 0.f;
        if (srow < chunk) f8 = *(const float8_t*)(dbase + (long)eid[srow]*64 + seg8*8);
        if (tid < 96 && mm < chunk) dirv = dirbase[(long)eid[mm]*3 + ii];
        // prime group-0 tab gathers
        uint32_t gA[4]; uint2_t gB[4];
        #pragma unroll
        for (int r = 0; r < 4; r++){
            int s = sid[q*4 + r];
            gA[r] = *(const uint32_t*)(ta + (long)(s*64 + d)*2);
            gB[r] = *(const uint2_t*)(tb + (long)(s*64 + d)*4);
        }

        for (int sg = 0; sg < nsg; sg++){
            int buf = sg & 1;
            // write staged A (cvt_pk hi/lo, conflict-free b128) + dirs
            {
                union { int4_t i; short8 s; } H, L;
                #pragma unroll
                for (int p = 0; p < 4; p++){
                    float a0 = f8[2*p], a1 = f8[2*p+1];
                    uint32_t hp, lp;
                    asm("v_cvt_pk_bf16_f32 %0, %1, %2" : "=v"(hp) : "v"(a0), "v"(a1));
                    float r0 = asf_lo(hp), r1 = asf_hi(hp);
                    asm("v_cvt_pk_bf16_f32 %0, %1, %2" : "=v"(lp) : "v"(a0 - r0), "v"(a1 - r1));
                    H.i[p] = (int)hp; L.i[p] = (int)lp;
                }
                int o = srow*64 + ((seg8 ^ (srow & 7))*8);
                *(short8*)&AHs[buf][o] = H.s;
                *(short8*)&ALs[buf][o] = L.s;
                if (tid < 96) dls[buf][mm][ii] = dirv;
            }
            // prefetch next supergroup's rows + dirs (in flight across barrier)
            float8_t f8n = z8; float dirn = 0.f;
            {
                int nb = (sg + 1)*32;
                if (nb < chunk){
                    int ri = nb + srow;
                    if (ri < chunk) f8n = *(const float8_t*)(dbase + (long)eid[ri]*64 + seg8*8);
                    int ri2 = nb + mm;
                    if (tid < 96 && ri2 < chunk) dirn = dirbase[(long)eid[ri2]*3 + ii];
                }
            }
            __syncthreads();

            int gmax = ngroups - sg*2; if (gmax > 2) gmax = 2;
            for (int g2 = 0; g2 < gmax; g2++){
                int gg = sg*2 + g2;
                // rolling depth-1 gather prefetch
                uint32_t gAn[4] = {0,0,0,0};
                uint2_t  gBn[4] = {{0,0},{0,0},{0,0},{0,0}};
                if (gg + 1 < ngroups){
                    int mrb2 = (gg+1)*16 + q*4;
                    #pragma unroll
                    for (int r = 0; r < 4; r++){
                        int s = sid[mrb2 + r];
                        gAn[r] = *(const uint32_t*)(ta + (long)(s*64 + d)*2);
                        gBn[r] = *(const uint2_t*)(tb + (long)(s*64 + d)*4);
                    }
                }
                // A fragments from swizzled LDS (conflict-free b128)
                int ro = g2*16 + c16;
                int sw = ro & 7;
                short8 ah0 = *(short8*)&AHs[buf][ro*64 + ((q ^ sw)*8)];
                short8 ah1 = *(short8*)&AHs[buf][ro*64 + (((4 + q) ^ sw)*8)];
                short8 al0 = *(short8*)&ALs[buf][ro*64 + ((q ^ sw)*8)];
                short8 al1 = *(short8*)&ALs[buf][ro*64 + (((4 + q) ^ sw)*8)];

                float4_t C[3];
                #pragma unroll
                for (int ni = 0; ni < 3; ni++){
                    float4_t acc = z4;
                    acc = __builtin_amdgcn_mfma_f32_16x16x32_bf16(ah0, bhf[ni][0], acc, 0, 0, 0);
                    acc = __builtin_amdgcn_mfma_f32_16x16x32_bf16(ah1, bhf[ni][1], acc, 0, 0, 0);
                    acc = __builtin_amdgcn_mfma_f32_16x16x32_bf16(ah0, blf[ni][0], acc, 0, 0, 0);
                    acc = __builtin_amdgcn_mfma_f32_16x16x32_bf16(ah1, blf[ni][1], acc, 0, 0, 0);
                    acc = __builtin_amdgcn_mfma_f32_16x16x32_bf16(al0, bhf[ni][0], acc, 0, 0, 0);
                    acc = __builtin_amdgcn_mfma_f32_16x16x32_bf16(al1, bhf[ni][1], acc, 0, 0, 0);
                    C[ni] = acc;
                }

                // epilogue: phi = we*hx folded via bf16 gather tables
                int mrb = g2*16 + q*4;
                #pragma unroll
                for (int r = 0; r < 4; r++){
                    int mr = mrb + r;
                    float hs  = asf_lo(gA[r]);
                    float hvs = asf_hi(gA[r]);
                    float hv0 = asf_lo(gB[r][0]);
                    float hv1 = asf_hi(gB[r][0]);
                    float hv2 = asf_lo(gB[r][1]);
                    acc_s += C[0][r] * hs;
                    float pvs = C[2][r] * hvs;
                    acc_v0 += C[1][r]*hv0 + pvs * dls[buf][mr][0];
                    acc_v1 += C[1][r]*hv1 + pvs * dls[buf][mr][1];
                    acc_v2 += C[1][r]*hv2 + pvs * dls[buf][mr][2];
                }
                #pragma unroll
                for (int r = 0; r < 4; r++){ gA[r] = gAn[r]; gB[r] = gBn[r]; }
            }
            f8 = f8n; dirv = dirn;
        }
    }

    // cross-quad reduction (C rows live in different quads)
    acc_s  += __shfl_xor(acc_s, 16);  acc_s  += __shfl_xor(acc_s, 32);
    acc_v0 += __shfl_xor(acc_v0, 16); acc_v0 += __shfl_xor(acc_v0, 32);
    acc_v1 += __shfl_xor(acc_v1, 16); acc_v1 += __shfl_xor(acc_v1, 32);
    acc_v2 += __shfl_xor(acc_v2, 16); acc_v2 += __shfl_xor(acc_v2, 32);
    if (l < 16){
        float* zp = zbuf + ((long)(t*1024 + node))*256;
        zp[d] = acc_s;
        zp[64 + d*3 + 0] = acc_v0;
        zp[64 + d*3 + 1] = acc_v1;
        zp[64 + d*3 + 2] = acc_v2;
    }
}

// ================= batched node update: block = (type, 4 nodes) ==============
__global__ __launch_bounds__(256) void update_kernel(
    const float* __restrict__ W_V, const float* __restrict__ W_U,
    const float* __restrict__ W_g1, const float* __restrict__ W_g2,
    const float* __restrict__ zbuf, float* __restrict__ out)
{
    int b = blockIdx.x;
    int t = b >> 8, tp = t + 1;
    int nb = (b & 255) * UNPB;
    int tid = threadIdx.x;

    __shared__ float zls[UNPB][256];
    __shared__ float Vv[UNPB][64][3], Uv[UNPB][64][3];
    __shared__ float gin[UNPB][128];
    __shared__ float hid[UNPB][128];
    __shared__ float aL[UNPB][192];
    __shared__ float vdot[UNPB][64];

    {   // load z: UNPB*256 floats, one float4 per thread
        int n = tid >> 6, c = tid & 63;
        *(float4_t*)&zls[n][c*4] =
            *(const float4_t*)(zbuf + ((long)(t*1024 + nb + n))*256 + c*4);
    }
    __syncthreads();

    {   // Vv/Uv: thread = (node n, feature f); zls broadcast across wave
        int f = tid & 63, n = tid >> 6;
        const float* wv = W_V + (long)tp*4096;
        const float* wu = W_U + (long)tp*4096;
        float av0=0,av1=0,av2=0,au0=0,au1=0,au2=0;
        #pragma unroll 4
        for (int dd = 0; dd < 64; dd++){
            float wvv = wv[dd*64 + f], wuu = wu[dd*64 + f];
            float z0 = zls[n][64 + dd*3 + 0];
            float z1 = zls[n][64 + dd*3 + 1];
            float z2 = zls[n][64 + dd*3 + 2];
            av0 += z0*wvv; av1 += z1*wvv; av2 += z2*wvv;
            au0 += z0*wuu; au1 += z1*wuu; au2 += z2*wuu;
        }
        Vv[n][f][0]=av0; Vv[n][f][1]=av1; Vv[n][f][2]=av2;
        Uv[n][f][0]=au0; Uv[n][f][1]=au1; Uv[n][f][2]=au2;
    }
    __syncthreads();

    {   // gin + vdot
        int n = tid >> 6, f = tid & 63;
        float v0=Vv[n][f][0], v1=Vv[n][f][1], v2=Vv[n][f][2];
        float u0=Uv[n][f][0], u1=Uv[n][f][1], u2=Uv[n][f][2];
        gin[n][f]      = zls[n][f];
        gin[n][64 + f] = v0*v0 + v1*v1 + v2*v2;
        vdot[n][f]     = u0*v0 + u1*v1 + u2*v2;
    }
    __syncthreads();

    {   // g1: 128 hidden cols x 2 node-groups
        int h = tid & 127, ng = tid >> 7;
        const float* w1 = W_g1 + (long)tp*16384;
        float a0=0, a1=0;
        #pragma unroll 4
        for (int c = 0; c < 128; c++){
            float w = w1[c*128 + h];
            a0 += gin[ng*2+0][c]*w;
            a1 += gin[ng*2+1][c]*w;
        }
        hid[ng*2+0][h] = silu_f(a0);
        hid[ng*2+1][h] = silu_f(a1);
    }
    __syncthreads();

    if (tid < 192){   // g2: 192 cols, 4 nodes each
        const float* w2 = W_g2 + (long)tp*24576;
        float a0=0,a1=0,a2=0,a3=0;
        #pragma unroll 4
        for (int h = 0; h < 128; h++){
            float w = w2[h*192 + tid];
            a0 += hid[0][h]*w; a1 += hid[1][h]*w;
            a2 += hid[2][h]*w; a3 += hid[3][h]*w;
        }
        aL[0][tid]=a0; aL[1][tid]=a1; aL[2][tid]=a2; aL[3][tid]=a3;
    }
    __syncthreads();

    {   // scalar + vector update
        int n = tid >> 6, f = tid & 63;
        float upd = aL[n][128 + f]*vdot[n][f] + aL[n][f];
        atomicAdd(&out[(nb + n)*256 + f], upd);
        float g = aL[n][64 + f];
        #pragma unroll
        for (int i = 0; i < 3; i++){
            float updv = Uv[n][f][i] * g;
            atomicAdd(&out[(nb + n)*256 + 64 + f*3 + i], updv);
        }
    }
}

// ================= fused fallback (previous proven kernel) ===================
__global__ __launch_bounds__(256) void main_kernel(
    const float* __restrict__ dist, const float* __restrict__ dirs,
    const float* __restrict__ W_V, const float* __restrict__ W_U,
    const float* __restrict__ W_g1, const float* __restrict__ W_g2,
    const ushort_t* __restrict__ tabA, const ushort_t* __restrict__ tabB,
    const short* __restrict__ fragH, const short* __restrict__ fragL,
    const int* __restrict__ counts, const int* __restrict__ offs, const int* __restrict__ sorted,
    float* __restrict__ out)
{
    int b = blockIdx.x;
    int t = b >> 10, node = b & 1023, tp = t + 1;
    const ushort_t* ta = tabA + ((t == 0) ? 0 : (t == 1 ? 32768 : 163840));
    const ushort_t* tb = tabB + ((t == 0) ? 0 : (t == 1 ? 65536 : 327680));
    const float* dbase = dist + (long)tp*E_EDGES*64;
    const float* dirbase = dirs + (long)tp*E_EDGES*3;

    int tid = threadIdx.x;
    int w = tid >> 6, l = tid & 63;
    int q = l >> 4, c16 = l & 15;
    int d = w*16 + c16;

    __shared__ short AH[2][2][64][8];
    __shared__ short AL[2][2][64][8];
    __shared__ float dls[2][16][3];
    __shared__ int eid[MAXCHUNK];
    __shared__ int sid[MAXCHUNK];
    __shared__ float zs[64];
    __shared__ float zv[64][3];
    __shared__ float VvL[192], UvL[192];
    __shared__ float gin[128], hidl[128], aLrr[192], vdotL[64];

    short8 bhf[3][2], blf[3][2];
    #pragma unroll
    for (int ni = 0; ni < 3; ni++){
        int nt = w + ni*4;
        #pragma unroll
        for (int ks = 0; ks < 2; ks++){
            long base = (long)t*12288 + ((nt*2 + ks)*64 + l)*8;
            bhf[ni][ks] = *(const short8*)(fragH + base);
            blf[ni][ks] = *(const short8*)(fragL + base);
        }
    }

    float acc_s = 0.f, acc_v0 = 0.f, acc_v1 = 0.f, acc_v2 = 0.f;

    int deg   = counts[t*1024 + node];
    int start = offs[t*1024 + node];

    int m = tid >> 4, seg = tid & 15;
    int ks_w = seg >> 3, quad_w = (seg >> 1) & 3, j0_w = (seg & 1)*4;
    int lane2 = m | (quad_w << 4);
    int mm = tid / 3, ii = tid - mm*3;

    const float4_t z4 = {0.f,0.f,0.f,0.f};

    for (int cbase = 0; cbase < deg; cbase += MAXCHUNK){
        int chunk = deg - cbase; if (chunk > MAXCHUNK) chunk = MAXCHUNK;
        __syncthreads();
        {
            int v = 0;
            if (tid < chunk) v = sorted[(long)start + cbase + tid];
            eid[tid] = v & 131071;
            sid[tid] = ((unsigned)v) >> 17;
        }
        __syncthreads();

        int ngroups = (chunk + 15) >> 4;
        float4_t dv = z4;
        if (m < chunk) dv = *(const float4_t*)(dbase + (long)eid[m]*64 + seg*4);
        float dirv = 0.f;
        if (tid < 48 && mm < chunk) dirv = dirbase[(long)eid[mm]*3 + ii];
        uint32_t gA[4]; uint2_t gB[4];
        #pragma unroll
        for (int r = 0; r < 4; r++){
            int s = sid[q*4 + r];
            gA[r] = *(const uint32_t*)(ta + (long)(s*64 + d)*2);
            gB[r] = *(const uint2_t*)(tb + (long)(s*64 + d)*4);
        }

        for (int g = 0; g < ngroups; g++){
            int buf = g & 1;
            {
                short4_t h4, l4;
                #pragma unroll
                for (int jj = 0; jj < 4; jj++){
                    short hi = f2bf_rne(dv[jj]);
                    h4[jj] = hi;
                    l4[jj] = f2bf_rne(dv[jj] - bf2f(hi));
                }
                *(short4_t*)&AH[buf][ks_w][lane2][j0_w] = h4;
                *(short4_t*)&AL[buf][ks_w][lane2][j0_w] = l4;
                if (tid < 48) dls[buf][mm][ii] = dirv;
            }
            float4_t dvn = z4; float dirn = 0.f;
            uint32_t gAn[4] = {0,0,0,0}; uint2_t gBn[4] = {{0,0},{0,0},{0,0},{0,0}};
            if (g + 1 < ngroups){
                int li = (g+1)*16 + m;
                if (li < chunk) dvn = *(const float4_t*)(dbase + (long)eid[li]*64 + seg*4);
                int li2 = (g+1)*16 + mm;
                if (tid < 48 && li2 < chunk) dirn = dirbase[(long)eid[li2]*3 + ii];
                #pragma unroll
                for (int r = 0; r < 4; r++){
                    int s = sid[(g+1)*16 + q*4 + r];
                    gAn[r] = *(const uint32_t*)(ta + (long)(s*64 + d)*2);
                    gBn[r] = *(const uint2_t*)(tb + (long)(s*64 + d)*4);
                }
            }
            __syncthreads();

            short8 ah0 = *(short8*)&AH[buf][0][l][0];
            short8 ah1 = *(short8*)&AH[buf][1][l][0];
            short8 al0 = *(short8*)&AL[buf][0][l][0];
            short8 al1 = *(short8*)&AL[buf][1][l][0];
            float4_t C[3];
            #pragma unroll
            for (int ni = 0; ni < 3; ni++){
                float4_t acc = z4;
                acc = __builtin_amdgcn_mfma_f32_16x16x32_bf16(ah0, bhf[ni][0], acc, 0, 0, 0);
                acc = __builtin_amdgcn_mfma_f32_16x16x32_bf16(ah1, bhf[ni][1], acc, 0, 0, 0);
                acc = __builtin_amdgcn_mfma_f32_16x16x32_bf16(ah0, blf[ni][0], acc, 0, 0, 0);
                acc = __builtin_amdgcn_mfma_f32_16x16x32_bf16(ah1, blf[ni][1], acc, 0, 0, 0);
                acc = __builtin_amdgcn_mfma_f32_16x16x32_bf16(al0, bhf[ni][0], acc, 0, 0, 0);
                acc = __builtin_amdgcn_mfma_f32_16x16x32_bf16(al1, bhf[ni][1], acc, 0, 0, 0);
                C[ni] = acc;
            }

            #pragma unroll
            for (int r = 0; r < 4; r++){
                int mr = q*4 + r;
                float hs  = asf_lo(gA[r]);
                float hvs = asf_hi(gA[r]);
                float hv0 = asf_lo(gB[r][0]);
                float hv1 = asf_hi(gB[r][0]);
                float hv2 = asf_lo(gB[r][1]);
                acc_s += C[0][r] * hs;
                float pvs = C[2][r] * hvs;
                acc_v0 += C[1][r]*hv0 + pvs * dls[buf][mr][0];
                acc_v1 += C[1][r]*hv1 + pvs * dls[buf][mr][1];
                acc_v2 += C[1][r]*hv2 + pvs * dls[buf][mr][2];
            }
            dv = dvn; dirv = dirn;
            #pragma unroll
            for (int r = 0; r < 4; r++){ gA[r] = gAn[r]; gB[r] = gBn[r]; }
        }
    }

    acc_s  += __shfl_xor(acc_s, 16);  acc_s  += __shfl_xor(acc_s, 32);
    acc_v0 += __shfl_xor(acc_v0, 16); acc_v0 += __shfl_xor(acc_v0, 32);
    acc_v1 += __shfl_xor(acc_v1, 16); acc_v1 += __shfl_xor(acc_v1, 32);
    acc_v2 += __shfl_xor(acc_v2, 16); acc_v2 += __shfl_xor(acc_v2, 32);
    __syncthreads();
    if (l < 16){
        zs[d] = acc_s;
        zv[d][0] = acc_v0; zv[d][1] = acc_v1; zv[d][2] = acc_v2;
    }
    __syncthreads();

    if (tid < 192){
        int i = tid >> 6, f = tid & 63;
        const float* wv = W_V + (long)tp*64*64;
        const float* wu = W_U + (long)tp*64*64;
        float av = 0.f, au = 0.f;
        #pragma unroll 8
        for (int dd = 0; dd < 64; dd++){
            float z = zv[dd][i];
            av += z * wv[dd*64 + f];
            au += z * wu[dd*64 + f];
        }
        VvL[f*3 + i] = av;
        UvL[f*3 + i] = au;
    }
    __syncthreads();
    if (tid < 64){
        int f = tid;
        float v0 = VvL[f*3], v1 = VvL[f*3+1], v2 = VvL[f*3+2];
        float u0 = UvL[f*3], u1 = UvL[f*3+1], u2 = UvL[f*3+2];
        gin[f] = zs[f];
        gin[64 + f] = v0*v0 + v1*v1 + v2*v2;
        vdotL[f] = u0*v0 + u1*v1 + u2*v2;
    }
    __syncthreads();
    if (tid < 128){
        const float* w1 = W_g1 + (long)tp*128*128;
        float acc = 0.f;
        #pragma unroll 8
        for (int c = 0; c < 128; c++) acc += gin[c] * w1[c*128 + tid];
        hidl[tid] = silu_f(acc);
    }
    __syncthreads();
    if (tid < 192){
        const float* w2 = W_g2 + (long)tp*128*192;
        float acc = 0.f;
        #pragma unroll 8
        for (int h = 0; h < 128; h++) acc += hidl[h] * w2[h*192 + tid];
        aLrr[tid] = acc;
    }
    __syncthreads();
    if (tid < 64){
        int f = tid;
        float upd = aLrr[128 + f] * vdotL[f] + aLrr[f];
        atomicAdd(&out[node*256 + f], upd);
    }
    if (tid < 192){
        int i = tid >> 6, f = tid & 63;
        float updv = UvL[f*3 + i] * aLrr[64 + f];
        atomicAdd(&out[node*256 + 64 + f*3 + i], updv);
    }
}

// ================= launcher ==================================================
extern "C" void kernel_launch(void* const* d_in, const int* in_sizes, int n_in,
                              void* d_out, int out_size, void* d_ws, size_t ws_size,
                              hipStream_t stream){
    const float* s_elec  = (const float*)d_in[0];
    const float* v_elec  = (const float*)d_in[1];
    const float* s_nuc   = (const float*)d_in[2];
    const float* v_nuc   = (const float*)d_in[3];
    const float* dist    = (const float*)d_in[4];
    const float* dirs    = (const float*)d_in[5];
    const float* W_w     = (const float*)d_in[6];
    const float* W_h1    = (const float*)d_in[7];
    const float* W_h2    = (const float*)d_in[8];
    const float* W_g1    = (const float*)d_in[9];
    const float* W_g2    = (const float*)d_in[10];
    const float* W_V     = (const float*)d_in[11];
    const float* W_U     = (const float*)d_in[12];
    const int* senders   = (const int*)d_in[13];
    const int* receivers = (const int*)d_in[14];
    float* out = (float*)d_out;
    char* ws = (char*)d_ws;

    // workspace layout (bytes)
    ushort_t* tabA  = (ushort_t*)(ws + 0);        // 589824 B  (h_s, h_vs) bf16
    ushort_t* tabB  = (ushort_t*)(ws + 589824);   // 1179648 B (hv0,hv1,hv2,pad) bf16
    short* fragH  = (short*)(ws + 1769472);       // 73728 B
    short* fragL  = (short*)(ws + 1843200);       // 73728 B
    int*   bh     = (int*)  (ws + 1916928);       // 196608 B
    int*   offs   = (int*)  (ws + 2113536);       // 12288 B
    int*   counts = (int*)  (ws + 2125824);       // 12288 B
    int*   sorted = (int*)  (ws + 2138112);       // 1572864 B -> end 3710976
    float* zbuf   = (float*)(ws + 3710976);       // 3145728 B -> end 6856704
    if (ws_size < 3710976) return;
    bool split = (ws_size >= 6856704);

    prep_kernel<<<dim3(595), dim3(256), 0, stream>>>(
        s_elec, v_elec, s_nuc, v_nuc, W_h1, W_h2, W_w, receivers,
        tabA, tabB, fragH, fragL, bh, out);
    scan_kernel<<<dim3(3), dim3(1024), 0, stream>>>(bh, offs, counts);
    scatter_kernel<<<dim3(48), dim3(256), 0, stream>>>(receivers, senders, bh, sorted);
    if (split){
        edge_kernel<<<dim3(3072), dim3(256), 0, stream>>>(
            dist, dirs, tabA, tabB, fragH, fragL, counts, offs, sorted, zbuf);
        update_kernel<<<dim3(768), dim3(256), 0, stream>>>(
            W_V, W_U, W_g1, W_g2, zbuf, out);
    } else {
        main_kernel<<<dim3(3072), dim3(256), 0, stream>>>(
            dist, dirs, W_V, W_U, W_g1, W_g2,
            tabA, tabB, fragH, fragL, counts, offs, sorted, out);
    }
}